// Round 6
// baseline (682.957 us; speedup 1.0000x reference)
//
#include <hip/hip_runtime.h>

#define SS  128
#define DD  512
#define NHH 8
#define DHH 64

typedef float  f4 __attribute__((ext_vector_type(4)));
typedef double d2 __attribute__((ext_vector_type(2)));

// ============ K1 qproj: q[b,o] = x_non[b].Wq[o,:] + bq[o]  (f64 acc) ==========
// 512 blocks = 64 b-tiles (16 rows) x 8 o-tiles (64 cols). K=512 in 8 chunks.
__global__ __launch_bounds__(256) void qproj_kernel(
    const float* __restrict__ x_non, const float* __restrict__ Wq,
    const float* __restrict__ bq, double* __restrict__ qws)
{
    const int tid = threadIdx.x;
    const int ot  = blockIdx.x & 7;
    const int bt  = blockIdx.x >> 3;
    const int r0  = tid >> 4, c0 = tid & 15;

    __shared__ __attribute__((aligned(16))) float Xs[16][68];
    __shared__ __attribute__((aligned(16))) float Ws[64][68];

    double acc[4] = {0.0, 0.0, 0.0, 0.0};

    for (int kc = 0; kc < 8; ++kc) {
        __syncthreads();
        {   // X tile 16x64
            int rr = tid >> 4, cc = (tid & 15) * 4;
            *(f4*)&Xs[rr][cc] = *(const f4*)(x_non + (size_t)(bt * 16 + rr) * DD + kc * 64 + cc);
        }
        #pragma unroll
        for (int p = 0; p < 4; ++p) {   // Wq tile 64x64
            int s = tid + 256 * p, rr = s >> 4, cc = (s & 15) * 4;
            *(f4*)&Ws[rr][cc] = *(const f4*)(Wq + (size_t)(ot * 64 + rr) * DD + kc * 64 + cc);
        }
        __syncthreads();
        #pragma unroll 4
        for (int kk = 0; kk < 64; ++kk) {
            double x = (double)Xs[r0][kk];
            #pragma unroll
            for (int j = 0; j < 4; ++j)
                acc[j] = fma(x, (double)Ws[c0 + 16 * j][kk], acc[j]);
        }
    }
    #pragma unroll
    for (int j = 0; j < 4; ++j) {
        int o = ot * 64 + c0 + 16 * j;
        qws[(size_t)(bt * 16 + r0) * DD + o] = acc[j] + (double)bq[o];
    }
}

// ============ K2 tproj: t[b,h,k] = sum_d Wk[h*64+d,k] * q[b,h*64+d] (f64) =====
// 2048 blocks = h(8) x bt(32: 32 b-rows) x kt(8: 64 k-cols). K=64 single pass.
// Also qbk[b,h] = q_h . bk_h  (kt==0 blocks).
__global__ __launch_bounds__(256) void tproj_kernel(
    const double* __restrict__ qws, const float* __restrict__ Wk,
    const float* __restrict__ bk, double* __restrict__ tws,
    double* __restrict__ qbkws)
{
    const int tid = threadIdx.x;
    const int h   = blockIdx.x & 7;
    const int bt  = (blockIdx.x >> 3) & 31;
    const int kt  = blockIdx.x >> 8;
    const int r0  = tid >> 4, c0 = tid & 15;

    __shared__ __attribute__((aligned(16))) double qs[32][66];
    __shared__ __attribute__((aligned(16))) float  Wks[64][68];

    // stage q tile: 32 b-rows x 64 d (coalesced)
    #pragma unroll
    for (int i = 0; i < 8; ++i) {
        int flat = tid + 256 * i;      // 2048 = 32 x 64
        int r = flat >> 6, d = flat & 63;
        qs[r][d] = qws[(size_t)(bt * 32 + r) * DD + h * DHH + d];
    }
    // stage Wk tile: 64 d-rows x 64 k
    #pragma unroll
    for (int i = 0; i < 4; ++i) {
        int flat = tid + 256 * i;      // 1024 f4
        int d = flat >> 4, c4 = (flat & 15) * 4;
        *(f4*)&Wks[d][c4] = *(const f4*)(Wk + (size_t)(h * DHH + d) * DD + kt * 64 + c4);
    }
    __syncthreads();

    double acc[2][4];
    #pragma unroll
    for (int i = 0; i < 2; ++i)
        #pragma unroll
        for (int j = 0; j < 4; ++j) acc[i][j] = 0.0;

    #pragma unroll 4
    for (int d = 0; d < 64; ++d) {
        double q0 = qs[r0][d];
        double q1 = qs[r0 + 16][d];
        #pragma unroll
        for (int j = 0; j < 4; ++j) {
            double w = (double)Wks[d][c0 + 16 * j];
            acc[0][j] = fma(q0, w, acc[0][j]);
            acc[1][j] = fma(q1, w, acc[1][j]);
        }
    }
    #pragma unroll
    for (int i = 0; i < 2; ++i)
        #pragma unroll
        for (int j = 0; j < 4; ++j) {
            int b = bt * 32 + r0 + 16 * i;
            int k = kt * 64 + c0 + 16 * j;
            tws[(size_t)b * (NHH * DD) + h * DD + k] = acc[i][j];
        }

    if (kt == 0 && tid < 32) {
        double s = 0.0;
        for (int d = 0; d < DHH; ++d)
            s = fma(qs[tid][d], (double)bk[h * DHH + d], s);
        qbkws[(size_t)(bt * 32 + tid) * NHH + h] = s;
    }
}

// ============ K3 core: qk = X.t + qbk -> floor/8, mask, softmax, u' ===========
__global__ __launch_bounds__(256) void core_kernel(
    const double* __restrict__ tws, const double* __restrict__ qbkws,
    const float* __restrict__ x_seq, const int* __restrict__ mask,
    float* __restrict__ uws)
{
    const int tid = threadIdx.x;
    const int b   = blockIdx.x;
    const float* Xb = x_seq + (size_t)b * (SS * DD);

    __shared__ __attribute__((aligned(16))) union {
        double Tl[NHH * DD];    // t[h*512+k]           (32 KB)
        double P[4][8][128];    // qk quarter-partials  (32 KB)
    } sh;
    __shared__ __attribute__((aligned(16))) float attn[8][128];
    __shared__ double qbks[8];
    __shared__ float  lsums[8];

    // ---- load T (coalesced) + qbk ----
    #pragma unroll
    for (int i = 0; i < 16; ++i)
        sh.Tl[tid + 256 * i] = tws[(size_t)b * (NHH * DD) + tid + 256 * i];
    if (tid < 8) qbks[tid] = qbkws[(size_t)b * NHH + tid];
    __syncthreads();

    // ---- qk partials: wave = k-quarter, lane = rows s=l, l+64 ----
    const int qw = tid >> 6, l = tid & 63;
    double acc0[8], acc1[8];
    #pragma unroll
    for (int h = 0; h < 8; ++h) { acc0[h] = 0.0; acc1[h] = 0.0; }
    {
        const int k0 = qw * 128;
        const float* xa = Xb + (size_t)l * DD + k0;
        const float* xc = xa + (size_t)64 * DD;
        for (int j = 0; j < 128; j += 4) {
            f4 xva = *(const f4*)(xa + j);
            f4 xvc = *(const f4*)(xc + j);
            #pragma unroll
            for (int h = 0; h < 8; ++h) {
                d2 t01 = *(const d2*)&sh.Tl[h * DD + k0 + j];
                d2 t23 = *(const d2*)&sh.Tl[h * DD + k0 + j + 2];
                acc0[h] = fma((double)xva[0], t01[0], acc0[h]);
                acc1[h] = fma((double)xvc[0], t01[0], acc1[h]);
                acc0[h] = fma((double)xva[1], t01[1], acc0[h]);
                acc1[h] = fma((double)xvc[1], t01[1], acc1[h]);
                acc0[h] = fma((double)xva[2], t23[0], acc0[h]);
                acc1[h] = fma((double)xvc[2], t23[0], acc1[h]);
                acc0[h] = fma((double)xva[3], t23[1], acc0[h]);
                acc1[h] = fma((double)xvc[3], t23[1], acc1[h]);
            }
        }
    }
    __syncthreads();                 // T fully read; P aliases it
    #pragma unroll
    for (int h = 0; h < 8; ++h) {
        sh.P[qw][h][l]      = acc0[h];
        sh.P[qw][h][l + 64] = acc1[h];
    }
    __syncthreads();

    // ---- reduce quarters, floor(/8), mask ----
    #pragma unroll
    for (int p = 0; p < 4; ++p) {
        int slot = tid + 256 * p;
        int h = slot >> 7, s2 = slot & 127;
        double tot = sh.P[0][h][s2] + sh.P[1][h][s2]
                   + sh.P[2][h][s2] + sh.P[3][h][s2] + qbks[h];
        double sc = floor(tot * 0.125);
        if (mask[(size_t)b * (NHH * SS) + slot] == 0) sc = -1e9;
        attn[h][s2] = (float)sc;
    }
    __syncthreads();

    // ---- softmax per head (32-lane groups), unnormalized ----
    {
        const int h = tid >> 5, i = tid & 31;
        float v[4], mx = -3e38f;
        #pragma unroll
        for (int jj = 0; jj < 4; ++jj) { v[jj] = attn[h][i + 32 * jj]; mx = fmaxf(mx, v[jj]); }
        #pragma unroll
        for (int off = 1; off < 32; off <<= 1) mx = fmaxf(mx, __shfl_xor(mx, off, 32));
        float sum = 0.f;
        #pragma unroll
        for (int jj = 0; jj < 4; ++jj) { v[jj] = expf(v[jj] - mx); sum += v[jj]; }
        #pragma unroll
        for (int off = 1; off < 32; off <<= 1) sum += __shfl_xor(sum, off, 32);
        #pragma unroll
        for (int jj = 0; jj < 4; ++jj) attn[h][i + 32 * jj] = v[jj];
        if (i == 0) lsums[h] = sum;
    }
    __syncthreads();

    // ---- u'[h,k] = (attn_h @ X)/lsum_h  (coalesced X) ----
    {
        float a1[8], a2[8];
        #pragma unroll
        for (int h = 0; h < 8; ++h) { a1[h] = 0.f; a2[h] = 0.f; }
        for (int s2 = 0; s2 < SS; s2 += 4) {
            f4 av[8];
            #pragma unroll
            for (int h = 0; h < 8; ++h) av[h] = *(const f4*)&attn[h][s2];
            #pragma unroll
            for (int e = 0; e < 4; ++e) {
                float x1 = Xb[(size_t)(s2 + e) * DD + tid];
                float x2 = Xb[(size_t)(s2 + e) * DD + tid + 256];
                #pragma unroll
                for (int h = 0; h < 8; ++h) {
                    a1[h] = fmaf(av[h][e], x1, a1[h]);
                    a2[h] = fmaf(av[h][e], x2, a2[h]);
                }
            }
        }
        #pragma unroll
        for (int h = 0; h < 8; ++h) {
            float inv = 1.0f / lsums[h];
            uws[((size_t)b * NHH + h) * DD + tid]       = a1[h] * inv;
            uws[((size_t)b * NHH + h) * DD + tid + 256] = a2[h] * inv;
        }
    }
}

// ============ K3b core fallback (R5-proven: t computed in-block) ==============
__global__ __launch_bounds__(256) void core_fallback_kernel(
    const double* __restrict__ qws, const float* __restrict__ x_seq,
    const int* __restrict__ mask, const float* __restrict__ Wk,
    const float* __restrict__ bk, float* __restrict__ uws)
{
    const int tid = threadIdx.x;
    const int b   = blockIdx.x;
    const float* Xb = x_seq + (size_t)b * (SS * DD);

    __shared__ __attribute__((aligned(16))) union {
        double T[8][512];
        double P[4][8][128];
    } sh;
    __shared__ __attribute__((aligned(16))) union {
        double qd[512];
        float  attn[8][128];
    } sh2;
    __shared__ double qbks[8];
    __shared__ float  lsums[8];

    sh2.qd[tid]       = qws[(size_t)b * DD + tid];
    sh2.qd[tid + 256] = qws[(size_t)b * DD + tid + 256];
    __syncthreads();

    if (tid < 64) {
        const int h = tid >> 3, part = tid & 7;
        double s = 0.0;
        #pragma unroll
        for (int ii = 0; ii < 8; ++ii) {
            int d = part * 8 + ii;
            s = fma(sh2.qd[h * DHH + d], (double)bk[h * DHH + d], s);
        }
        s += __shfl_xor(s, 1);
        s += __shfl_xor(s, 2);
        s += __shfl_xor(s, 4);
        if (part == 0) qbks[h] = s;
    }

    {
        const int kg = tid & 127, dh = tid >> 7;
        const int k4 = kg * 4;
        for (int hg = 0; hg < 2; ++hg) {
            double tacc[4][4];
            #pragma unroll
            for (int h4 = 0; h4 < 4; ++h4) {
                const int h = hg * 4 + h4;
                const float* wp = Wk + ((size_t)(h * DHH + dh * 32)) * DD + k4;
                double t0 = 0, t1 = 0, t2 = 0, t3 = 0;
                for (int d = 0; d < 32; ++d) {
                    f4 wv = *(const f4*)(wp + (size_t)d * DD);
                    double qv = sh2.qd[h * DHH + dh * 32 + d];
                    t0 = fma((double)wv[0], qv, t0);
                    t1 = fma((double)wv[1], qv, t1);
                    t2 = fma((double)wv[2], qv, t2);
                    t3 = fma((double)wv[3], qv, t3);
                }
                tacc[h4][0] = t0; tacc[h4][1] = t1; tacc[h4][2] = t2; tacc[h4][3] = t3;
            }
            if (dh == 1) {
                #pragma unroll
                for (int h4 = 0; h4 < 4; ++h4)
                    #pragma unroll
                    for (int e = 0; e < 4; ++e)
                        sh.T[hg * 4 + h4][k4 + e] = tacc[h4][e];
            }
            __syncthreads();
            if (dh == 0) {
                #pragma unroll
                for (int h4 = 0; h4 < 4; ++h4)
                    #pragma unroll
                    for (int e = 0; e < 4; ++e)
                        sh.T[hg * 4 + h4][k4 + e] += tacc[h4][e];
            }
            __syncthreads();
        }
    }

    const int qw = tid >> 6, l = tid & 63;
    double acc0[8], acc1[8];
    #pragma unroll
    for (int h = 0; h < 8; ++h) { acc0[h] = 0.0; acc1[h] = 0.0; }
    {
        const int k0 = qw * 128;
        const float* xa = Xb + (size_t)l * DD + k0;
        const float* xc = xa + (size_t)64 * DD;
        for (int j = 0; j < 128; j += 4) {
            f4 xva = *(const f4*)(xa + j);
            f4 xvc = *(const f4*)(xc + j);
            #pragma unroll
            for (int h = 0; h < 8; ++h) {
                d2 t01 = *(const d2*)&sh.T[h][k0 + j];
                d2 t23 = *(const d2*)&sh.T[h][k0 + j + 2];
                acc0[h] = fma((double)xva[0], t01[0], acc0[h]);
                acc1[h] = fma((double)xvc[0], t01[0], acc1[h]);
                acc0[h] = fma((double)xva[1], t01[1], acc0[h]);
                acc1[h] = fma((double)xvc[1], t01[1], acc1[h]);
                acc0[h] = fma((double)xva[2], t23[0], acc0[h]);
                acc1[h] = fma((double)xvc[2], t23[0], acc1[h]);
                acc0[h] = fma((double)xva[3], t23[1], acc0[h]);
                acc1[h] = fma((double)xvc[3], t23[1], acc1[h]);
            }
        }
    }
    __syncthreads();
    #pragma unroll
    for (int h = 0; h < 8; ++h) {
        sh.P[qw][h][l]      = acc0[h];
        sh.P[qw][h][l + 64] = acc1[h];
    }
    __syncthreads();

    #pragma unroll
    for (int p = 0; p < 4; ++p) {
        int slot = tid + 256 * p;
        int h = slot >> 7, s2 = slot & 127;
        double tot = sh.P[0][h][s2] + sh.P[1][h][s2]
                   + sh.P[2][h][s2] + sh.P[3][h][s2] + qbks[h];
        double sc = floor(tot * 0.125);
        if (mask[(size_t)b * (NHH * SS) + slot] == 0) sc = -1e9;
        sh2.attn[h][s2] = (float)sc;
    }
    __syncthreads();

    {
        const int h = tid >> 5, i = tid & 31;
        float v[4], mx = -3e38f;
        #pragma unroll
        for (int jj = 0; jj < 4; ++jj) { v[jj] = sh2.attn[h][i + 32 * jj]; mx = fmaxf(mx, v[jj]); }
        #pragma unroll
        for (int off = 1; off < 32; off <<= 1) mx = fmaxf(mx, __shfl_xor(mx, off, 32));
        float sum = 0.f;
        #pragma unroll
        for (int jj = 0; jj < 4; ++jj) { v[jj] = expf(v[jj] - mx); sum += v[jj]; }
        #pragma unroll
        for (int off = 1; off < 32; off <<= 1) sum += __shfl_xor(sum, off, 32);
        #pragma unroll
        for (int jj = 0; jj < 4; ++jj) sh2.attn[h][i + 32 * jj] = v[jj];
        if (i == 0) lsums[h] = sum;
    }
    __syncthreads();

    {
        float a1[8], a2[8];
        #pragma unroll
        for (int h = 0; h < 8; ++h) { a1[h] = 0.f; a2[h] = 0.f; }
        for (int s2 = 0; s2 < SS; s2 += 4) {
            f4 av[8];
            #pragma unroll
            for (int h = 0; h < 8; ++h) av[h] = *(const f4*)&sh2.attn[h][s2];
            #pragma unroll
            for (int e = 0; e < 4; ++e) {
                float x1 = Xb[(size_t)(s2 + e) * DD + tid];
                float x2 = Xb[(size_t)(s2 + e) * DD + tid + 256];
                #pragma unroll
                for (int h = 0; h < 8; ++h) {
                    a1[h] = fmaf(av[h][e], x1, a1[h]);
                    a2[h] = fmaf(av[h][e], x2, a2[h]);
                }
            }
        }
        #pragma unroll
        for (int h = 0; h < 8; ++h) {
            float inv = 1.0f / lsums[h];
            uws[((size_t)b * NHH + h) * DD + tid]       = a1[h] * inv;
            uws[((size_t)b * NHH + h) * DD + tid + 256] = a2[h] * inv;
        }
    }
}

// ============ K4 zout: z[b,o] = u'[b,h(o),:].Wv[o,:] + bv[o]  (f32) ===========
// 512 blocks = bt(32: 32 rows) x ot(16: 32 cols). Head h = ot>>1.
__global__ __launch_bounds__(256) void zout_kernel(
    const float* __restrict__ uws, const float* __restrict__ Wv,
    const float* __restrict__ bv, float* __restrict__ out)
{
    const int tid = threadIdx.x;
    const int ot  = blockIdx.x & 15;
    const int bt  = blockIdx.x >> 4;
    const int h   = ot >> 1;
    const int r0  = tid >> 4, c0 = tid & 15;

    __shared__ __attribute__((aligned(16))) float Us[32][68];
    __shared__ __attribute__((aligned(16))) float Ws[32][68];

    float acc[2][2] = {{0.f, 0.f}, {0.f, 0.f}};

    for (int kc = 0; kc < 8; ++kc) {
        __syncthreads();
        #pragma unroll
        for (int p = 0; p < 2; ++p) {
            int s = tid + 256 * p, rr = s >> 4, cc = (s & 15) * 4;
            *(f4*)&Us[rr][cc] =
                *(const f4*)(uws + ((size_t)(bt * 32 + rr) * NHH + h) * DD + kc * 64 + cc);
            *(f4*)&Ws[rr][cc] =
                *(const f4*)(Wv + (size_t)(ot * 32 + rr) * DD + kc * 64 + cc);
        }
        __syncthreads();
        #pragma unroll 4
        for (int kk = 0; kk < 64; ++kk) {
            float u0 = Us[r0][kk];
            float u1 = Us[r0 + 16][kk];
            float w0 = Ws[c0][kk];
            float w1 = Ws[c0 + 16][kk];
            acc[0][0] = fmaf(u0, w0, acc[0][0]);
            acc[0][1] = fmaf(u0, w1, acc[0][1]);
            acc[1][0] = fmaf(u1, w0, acc[1][0]);
            acc[1][1] = fmaf(u1, w1, acc[1][1]);
        }
    }
    #pragma unroll
    for (int i = 0; i < 2; ++i)
        #pragma unroll
        for (int j = 0; j < 2; ++j) {
            int o = ot * 32 + c0 + 16 * j;
            out[(size_t)(bt * 32 + r0 + 16 * i) * DD + o] = acc[i][j] + bv[o];
        }
}

extern "C" void kernel_launch(void* const* d_in, const int* in_sizes, int n_in,
                              void* d_out, int out_size, void* d_ws, size_t ws_size,
                              hipStream_t stream) {
    const float* x_non = (const float*)d_in[0];
    const float* x_seq = (const float*)d_in[1];
    const int*   mask  = (const int*)d_in[2];
    const float* Wq    = (const float*)d_in[3];
    const float* bq    = (const float*)d_in[4];
    const float* Wk    = (const float*)d_in[5];
    const float* bk    = (const float*)d_in[6];
    const float* Wv    = (const float*)d_in[7];
    const float* bv    = (const float*)d_in[8];
    float*       out   = (float*)d_out;

    const size_t SZ_A   = (size_t)16 * 1024 * 1024;  // qws (4 MB) then uws (16 MB)
    const size_t SZ_T   = (size_t)32 * 1024 * 1024;  // tws f64
    const size_t SZ_QBK = (size_t)1024 * NHH * 8;    // 64 KB
    const size_t NEED   = SZ_A + SZ_T + SZ_QBK;      // 48.06 MB

    if (ws_size >= NEED) {
        double* qws   = (double*)d_ws;                       // dies before uws written
        float*  uws   = (float*)d_ws;                        // overlays qws
        double* tws   = (double*)((char*)d_ws + SZ_A);
        double* qbkws = (double*)((char*)d_ws + SZ_A + SZ_T);

        qproj_kernel<<<512, 256, 0, stream>>>(x_non, Wq, bq, qws);
        tproj_kernel<<<2048, 256, 0, stream>>>(qws, Wk, bk, tws, qbkws);
        core_kernel<<<1024, 256, 0, stream>>>(tws, qbkws, x_seq, mask, uws);
        zout_kernel<<<512, 256, 0, stream>>>(uws, Wv, bv, out);
    } else {
        // R5-proven 20 MB path
        double* qws = (double*)d_ws;
        float*  uws = (float*)((char*)d_ws + (size_t)1024 * DD * 8);
        qproj_kernel<<<512, 256, 0, stream>>>(x_non, Wq, bq, qws);
        core_fallback_kernel<<<1024, 256, 0, stream>>>(qws, x_seq, mask, Wk, bk, uws);
        zout_kernel<<<512, 256, 0, stream>>>(uws, Wv, bv, out);
    }
}